// Round 1
// baseline (905.449 us; speedup 1.0000x reference)
//
#include <hip/hip_runtime.h>

#define NVEC (64*64*64)   // 262144 vectors
#define KCB 1024          // codebook size
#define DIM 64            // codebook dim
#define EPS_GAP 4e-6f     // f32 top-2 gap below which we re-resolve in f64
#define FLAG_CAP NVEC     // flagged list can hold every vector -> no overflow

// ws layout (bytes):
//       0 : double loss_sum
//       8 : uint counts[1024]            (ends 4104)
//    4104 : uint flag_count
//    4112 : uint flagged[NVEC]           (ends 1052688)
// 1052688 : float  cnormf[1024]          (ends 1056784)
// 1056784 : double cnormd[1024]          (ends 1064976)

__global__ __launch_bounds__(256) void vq_cnorm(const float* __restrict__ cb,
                                                float* __restrict__ cnf,
                                                double* __restrict__ cnd) {
    int k = blockIdx.x * blockDim.x + threadIdx.x;
    if (k >= KCB) return;
    const float* row = cb + (size_t)k * DIM;
    double s = 0.0;
    #pragma unroll
    for (int i = 0; i < DIM; ++i) {
        double c = (double)row[i];
        s = fma(c, c, s);
    }
    cnf[k] = (float)s;
    cnd[k] = s;
}

__global__ __launch_bounds__(256) void vq_main(const float* __restrict__ inp,
                                               const float* __restrict__ cb,
                                               float* __restrict__ out,
                                               double* __restrict__ loss_sum,
                                               unsigned int* __restrict__ counts,
                                               unsigned int* __restrict__ flag_count,
                                               unsigned int* __restrict__ flagged,
                                               const float* __restrict__ cnf) {
    const int t = blockIdx.x * 256 + threadIdx.x;   // one vector per thread

    // load this thread's vector (16 x float4 = 64 floats) into registers
    const float4* __restrict__ xin = (const float4*)(inp + (size_t)t * DIM);
    float4 xv[16];
    #pragma unroll
    for (int i = 0; i < 16; ++i) xv[i] = xin[i];

    const float4* __restrict__ cb4 = (const float4*)cb;

    float b1 = 3.4e38f, b2 = 3.4e38f;   // best / second-best score
    int   bi = 0;
    for (int k = 0; k < KCB; ++k) {
        // codebook row via wave-uniform address -> scalar (s_load) path
        float dp0 = 0.f, dp1 = 0.f, dp2 = 0.f, dp3 = 0.f;
        #pragma unroll
        for (int i = 0; i < 16; ++i) {
            float4 c = cb4[k * 16 + i];
            dp0 = fmaf(xv[i].x, c.x, dp0);
            dp1 = fmaf(xv[i].y, c.y, dp1);
            dp2 = fmaf(xv[i].z, c.z, dp2);
            dp3 = fmaf(xv[i].w, c.w, dp3);
        }
        float dot = (dp0 + dp1) + (dp2 + dp3);
        float s = fmaf(-2.0f, dot, cnf[k]);   // ||c||^2 - 2 x.c  (row-constant ||x||^2 dropped)
        bool better = s < b1;                  // strict < keeps earliest index on ties
        b2 = better ? b1 : fminf(b2, s);
        b1 = better ? s  : b1;
        bi = better ? k  : bi;
    }

    float lpart = 0.0f;
    if ((b2 - b1) < EPS_GAP) {
        // ambiguous at f32 precision: defer to exact f64 repair kernel
        unsigned slot = atomicAdd(flag_count, 1u);
        flagged[slot] = (unsigned)t;           // slot < NVEC always
    } else {
        // commit: write codes, accumulate loss + count
        float4* __restrict__ o4 = (float4*)(out + (size_t)t * DIM);
        #pragma unroll
        for (int i = 0; i < 16; ++i) {
            float4 c = cb4[bi * 16 + i];
            o4[i] = c;
            float d0 = xv[i].x - c.x, d1 = xv[i].y - c.y;
            float d2 = xv[i].z - c.z, d3 = xv[i].w - c.w;
            lpart = fmaf(d0, d0, lpart);
            lpart = fmaf(d1, d1, lpart);
            lpart = fmaf(d2, d2, lpart);
            lpart = fmaf(d3, d3, lpart);
        }
        atomicAdd(&counts[bi], 1u);
    }

    // block-level loss reduction -> one f64 atomic per block
    __shared__ double red[256];
    red[threadIdx.x] = (double)lpart;
    __syncthreads();
    for (int s = 128; s > 0; s >>= 1) {
        if (threadIdx.x < s) red[threadIdx.x] += red[threadIdx.x + s];
        __syncthreads();
    }
    if (threadIdx.x == 0) atomicAdd(loss_sum, red[0]);
}

__global__ __launch_bounds__(256) void vq_repair(const float* __restrict__ inp,
                                                 const float* __restrict__ cb,
                                                 float* __restrict__ out,
                                                 double* __restrict__ loss_sum,
                                                 unsigned int* __restrict__ counts,
                                                 const unsigned int* __restrict__ flag_count,
                                                 const unsigned int* __restrict__ flagged,
                                                 const double* __restrict__ cnd) {
    __shared__ double sval[256];
    __shared__ int    sidx[256];
    unsigned total = *flag_count;
    if (total > FLAG_CAP) total = FLAG_CAP;

    for (unsigned j = blockIdx.x; j < total; j += gridDim.x) {
        int v = flagged[j];
        const float* __restrict__ x = inp + (size_t)v * DIM;

        // exact f64 scores; 4 codes per thread (strided)
        double bs = 1e300; int bk = 0;
        #pragma unroll
        for (int m = 0; m < 4; ++m) {
            int k = threadIdx.x + 256 * m;
            const float* row = cb + (size_t)k * DIM;
            double dot = 0.0;
            for (int i = 0; i < DIM; ++i)
                dot = fma((double)x[i], (double)row[i], dot);
            double s = fma(-2.0, dot, cnd[k]);
            if (s < bs || (s == bs && k < bk)) { bs = s; bk = k; }
        }
        sval[threadIdx.x] = bs;
        sidx[threadIdx.x] = bk;
        __syncthreads();
        for (int off = 128; off > 0; off >>= 1) {
            if (threadIdx.x < off) {
                double s2 = sval[threadIdx.x + off];
                int    k2 = sidx[threadIdx.x + off];
                if (s2 < sval[threadIdx.x] ||
                    (s2 == sval[threadIdx.x] && k2 < sidx[threadIdx.x])) {
                    sval[threadIdx.x] = s2;
                    sidx[threadIdx.x] = k2;
                }
            }
            __syncthreads();
        }
        int bkf = sidx[0];
        __syncthreads();

        // write codes + loss contribution for this vector
        double lp = 0.0;
        if (threadIdx.x < DIM) {
            float c = cb[(size_t)bkf * DIM + threadIdx.x];
            out[(size_t)v * DIM + threadIdx.x] = c;
            float d = x[threadIdx.x] - c;
            lp = (double)d * (double)d;
        }
        sval[threadIdx.x] = lp;
        __syncthreads();
        for (int off = 128; off > 0; off >>= 1) {
            if (threadIdx.x < off) sval[threadIdx.x] += sval[threadIdx.x + off];
            __syncthreads();
        }
        if (threadIdx.x == 0) {
            atomicAdd(loss_sum, sval[0]);
            atomicAdd(&counts[bkf], 1u);
        }
        __syncthreads();
    }
}

__global__ __launch_bounds__(256) void vq_finalize(float* __restrict__ out,
                                                   const double* __restrict__ loss_sum,
                                                   const unsigned int* __restrict__ counts) {
    __shared__ double red[256];
    double h = 0.0;
    for (int k = threadIdx.x; k < KCB; k += 256) {
        double p = (double)counts[k] / (double)NVEC;
        h += p * log(p + 1e-10);
    }
    red[threadIdx.x] = h;
    __syncthreads();
    for (int s = 128; s > 0; s >>= 1) {
        if (threadIdx.x < s) red[threadIdx.x] += red[threadIdx.x + s];
        __syncthreads();
    }
    if (threadIdx.x == 0) {
        out[(size_t)NVEC * DIM]     = (float)(0.25 * (*loss_sum) / (double)((size_t)NVEC * DIM));
        out[(size_t)NVEC * DIM + 1] = (float)exp(-red[0]);
    }
}

extern "C" void kernel_launch(void* const* d_in, const int* in_sizes, int n_in,
                              void* d_out, int out_size, void* d_ws, size_t ws_size,
                              hipStream_t stream) {
    const float* inp = (const float*)d_in[0];   // (64,64,64,64) f32
    const float* cb  = (const float*)d_in[1];   // (1024,64) f32
    float* out = (float*)d_out;                 // 16777216 + 2 floats

    char* ws = (char*)d_ws;
    double*       loss_sum   = (double*)(ws + 0);
    unsigned int* counts     = (unsigned int*)(ws + 8);
    unsigned int* flag_count = (unsigned int*)(ws + 4104);
    unsigned int* flagged    = (unsigned int*)(ws + 4112);
    float*        cnf        = (float*)(ws + 1052688);
    double*       cnd        = (double*)(ws + 1056784);

    hipMemsetAsync(ws, 0, 4108, stream);  // loss_sum, counts, flag_count
    vq_cnorm<<<dim3(4), dim3(256), 0, stream>>>(cb, cnf, cnd);
    vq_main<<<dim3(NVEC / 256), dim3(256), 0, stream>>>(inp, cb, out, loss_sum,
                                                        counts, flag_count, flagged, cnf);
    vq_repair<<<dim3(128), dim3(256), 0, stream>>>(inp, cb, out, loss_sum,
                                                   counts, flag_count, flagged, cnd);
    vq_finalize<<<dim3(1), dim3(256), 0, stream>>>(out, loss_sum, counts);
}

// Round 2
// 211.424 us; speedup vs baseline: 4.2826x; 4.2826x over previous
//
#include <hip/hip_runtime.h>

#define NVEC (64*64*64)   // 262144 vectors
#define KCB 1024          // codebook size
#define DIM 64            // codebook dim

typedef __attribute__((ext_vector_type(8))) short s16x8;   // 8 x bf16
typedef __attribute__((ext_vector_type(4))) float f32x4;

#define MFMA16(A, B, C) __builtin_amdgcn_mfma_f32_16x16x32_bf16((A), (B), (C), 0, 0, 0)

// ws layout (bytes):
//      0 : double loss_sum
//      8 : uint counts[1024]          (ends 4104, pad to 4112)
//   4112 : float cnf[1024]            (ends 8208, pad to 8224)
//   8224 : ushort cbh[1024*64]        (bf16 of -2c, hi)   ends 139296
// 139296 : ushort cbl[1024*64]        (bf16 of -2c, lo)   ends 270368

__device__ __forceinline__ unsigned short bf16rn(float f) {
    unsigned u = __float_as_uint(f);
    return (unsigned short)((u + 0x7fffu + ((u >> 16) & 1u)) >> 16);
}
__device__ __forceinline__ float bf2f(unsigned short h) {
    return __uint_as_float(((unsigned)h) << 16);
}

__global__ __launch_bounds__(256) void vq_prep(const float* __restrict__ cb,
                                               unsigned short* __restrict__ cbh,
                                               unsigned short* __restrict__ cbl,
                                               float* __restrict__ cnf) {
    int k = blockIdx.x * 256 + threadIdx.x;
    if (k >= KCB) return;
    const float* row = cb + (size_t)k * DIM;
    double s = 0.0;
    for (int d = 0; d < DIM; ++d) {
        float c = row[d];
        s = fma((double)c, (double)c, s);
        float m2 = -2.0f * c;                 // exact scale by -2
        unsigned short h = bf16rn(m2);
        cbh[k * DIM + d] = h;
        cbl[k * DIM + d] = bf16rn(m2 - bf2f(h));
    }
    cnf[k] = (float)s;
}

__global__ __launch_bounds__(256, 2) void vq_main(const float* __restrict__ inp,
                                                  const unsigned short* __restrict__ cbh,
                                                  const unsigned short* __restrict__ cbl,
                                                  const float* __restrict__ cnfg,
                                                  const float* __restrict__ cb,
                                                  float* __restrict__ out,
                                                  double* __restrict__ loss_sum,
                                                  unsigned int* __restrict__ counts) {
    __shared__ unsigned short chS[256 * 64];   // 32 KB, swizzled
    __shared__ unsigned short clS[256 * 64];   // 32 KB, swizzled
    __shared__ float cnS[KCB];                 // 4 KB

    const int tid  = threadIdx.x;
    const int lane = tid & 63;
    const int w    = tid >> 6;        // wave 0..3
    const int l15  = lane & 15;
    const int g    = lane >> 4;       // lane group 0..3
    const int vecbase = blockIdx.x * 256 + w * 64;

    // stage cnf (all 1024 floats) once
    ((float4*)cnS)[tid] = ((const float4*)cnfg)[tid];

    // ---- load this wave's 64 vectors, build hi/lo bf16 B-fragments ----
    // B[k][n]: lane l holds n = l&15, k = (l>>4)*8 + j  (frag0: k 0..31, frag1: k 32..63)
    s16x8 xh0[4], xh1[4], xl0[4], xl1[4];
    #pragma unroll
    for (int v = 0; v < 4; ++v) {
        int vid = vecbase + v * 16 + l15;
        const float4* xp = (const float4*)(inp + (size_t)vid * DIM);
        float4 a0 = xp[g * 2], a1 = xp[g * 2 + 1];
        float4 a2 = xp[8 + g * 2], a3 = xp[8 + g * 2 + 1];
        float f0[8] = {a0.x, a0.y, a0.z, a0.w, a1.x, a1.y, a1.z, a1.w};
        float f1[8] = {a2.x, a2.y, a2.z, a2.w, a3.x, a3.y, a3.z, a3.w};
        #pragma unroll
        for (int j = 0; j < 8; ++j) {
            unsigned short h0 = bf16rn(f0[j]);
            xh0[v][j] = (short)h0;
            xl0[v][j] = (short)bf16rn(f0[j] - bf2f(h0));
            unsigned short h1 = bf16rn(f1[j]);
            xh1[v][j] = (short)h1;
            xl1[v][j] = (short)bf16rn(f1[j] - bf2f(h1));
        }
    }

    float best[4] = {3.4e38f, 3.4e38f, 3.4e38f, 3.4e38f};
    int   bidx[4] = {0, 0, 0, 0};

    // ---- K-chunk loop: 4 chunks of 256 codes ----
    for (int chunk = 0; chunk < 4; ++chunk) {
        __syncthreads();   // protect LDS from previous chunk's readers (also orders cnS)
        const unsigned short* sH = cbh + chunk * 256 * DIM;
        const unsigned short* sL = cbl + chunk * 256 * DIM;
        #pragma unroll
        for (int it = 0; it < 8; ++it) {
            int gi   = it * 256 + tid;             // 16B-chunk index 0..2047
            int row  = gi >> 3;
            int slot = gi & 7;
            int dby  = row * 128 + ((slot * 16) ^ ((row & 7) << 4));
            *(int4*)((char*)chS + dby) = ((const int4*)sH)[gi];
            *(int4*)((char*)clS + dby) = ((const int4*)sL)[gi];
        }
        __syncthreads();

        for (int tile = 0; tile < 16; ++tile) {
            int tb   = tile * 16;
            int arow = tb + l15;
            int sw   = (arow & 7) << 4;
            int bo0  = arow * 128 + ((g * 16) ^ sw);
            int bo1  = arow * 128 + ((64 + g * 16) ^ sw);
            // A[m][k]: lane l holds m = l&15, k = (l>>4)*8 + j
            s16x8 Ah0 = *(const s16x8*)((const char*)chS + bo0);
            s16x8 Ah1 = *(const s16x8*)((const char*)chS + bo1);
            s16x8 Al0 = *(const s16x8*)((const char*)clS + bo0);
            s16x8 Al1 = *(const s16x8*)((const char*)clS + bo1);

            int kb = chunk * 256 + tb + g * 4;
            f32x4 cn4 = *(const f32x4*)(cnS + kb);   // acc init = ||c||^2 (broadcast read)

            f32x4 acc[4];
            #pragma unroll
            for (int v = 0; v < 4; ++v) acc[v] = cn4;
            #pragma unroll
            for (int v = 0; v < 4; ++v) acc[v] = MFMA16(Ah0, xh0[v], acc[v]);
            #pragma unroll
            for (int v = 0; v < 4; ++v) acc[v] = MFMA16(Ah1, xh1[v], acc[v]);
            #pragma unroll
            for (int v = 0; v < 4; ++v) acc[v] = MFMA16(Al0, xh0[v], acc[v]);
            #pragma unroll
            for (int v = 0; v < 4; ++v) acc[v] = MFMA16(Al1, xh1[v], acc[v]);
            #pragma unroll
            for (int v = 0; v < 4; ++v) acc[v] = MFMA16(Ah0, xl0[v], acc[v]);
            #pragma unroll
            for (int v = 0; v < 4; ++v) acc[v] = MFMA16(Ah1, xl1[v], acc[v]);

            // acc[v][r] = score of code (kb + r) vs vector (v*16 + l15)
            #pragma unroll
            for (int v = 0; v < 4; ++v) {
                #pragma unroll
                for (int r = 0; r < 4; ++r) {
                    float s = acc[v][r];
                    bool bet = s < best[v];
                    bidx[v] = bet ? (kb + r) : bidx[v];
                    best[v] = bet ? s : best[v];
                }
            }
        }
    }

    // ---- reduce argmin across the 4 lane groups (codes are split across g) ----
    #pragma unroll
    for (int v = 0; v < 4; ++v) {
        #pragma unroll
        for (int off = 16; off < 64; off <<= 1) {
            float ob = __shfl_xor(best[v], off);
            int   oi = __shfl_xor(bidx[v], off);
            if (ob < best[v] || (ob == best[v] && oi < bidx[v])) {
                best[v] = ob;
                bidx[v] = oi;
            }
        }
    }

    // ---- coalesced output write: wave region = 64 vectors = 16 KB contiguous ----
    float4* ob4 = (float4*)(out + (size_t)vecbase * DIM);
    #pragma unroll
    for (int v = 0; v < 4; ++v) {
        #pragma unroll
        for (int i = 0; i < 4; ++i) {
            int wv = i * 4 + g;                       // vector-in-set 0..15
            int bk = __shfl(bidx[v], wv);             // lane wv holds it post-reduction
            const float4* cr = (const float4*)(cb + (size_t)bk * DIM);
            float4 q = cr[l15];                       // 16 lanes -> full 256B row
            ob4[(v * 16 + wv) * 16 + l15] = q;        // 64 lanes -> 1KB contiguous
        }
    }

    // ---- loss (x reconstructed from hi+lo frags; rel err ~4e-6) + counts ----
    float lsum = 0.0f;
    #pragma unroll
    for (int v = 0; v < 4; ++v) {
        int bk = bidx[v];
        const float4* cr = (const float4*)(cb + (size_t)bk * DIM);
        float4 c0 = cr[g * 2], c1 = cr[g * 2 + 1];
        float4 c2 = cr[8 + g * 2], c3 = cr[8 + g * 2 + 1];
        float cf0[8] = {c0.x, c0.y, c0.z, c0.w, c1.x, c1.y, c1.z, c1.w};
        float cf1[8] = {c2.x, c2.y, c2.z, c2.w, c3.x, c3.y, c3.z, c3.w};
        #pragma unroll
        for (int j = 0; j < 8; ++j) {
            float xj = bf2f((unsigned short)xh0[v][j]) + bf2f((unsigned short)xl0[v][j]);
            float d  = xj - cf0[j];
            lsum = fmaf(d, d, lsum);
            float xk = bf2f((unsigned short)xh1[v][j]) + bf2f((unsigned short)xl1[v][j]);
            float e  = xk - cf1[j];
            lsum = fmaf(e, e, lsum);
        }
        if (g == 0) atomicAdd(&counts[bk], 1u);
    }
    double dsum = (double)lsum;
    #pragma unroll
    for (int off = 32; off > 0; off >>= 1) dsum += __shfl_xor(dsum, off);
    if (lane == 0) atomicAdd(loss_sum, dsum);
}

__global__ __launch_bounds__(256) void vq_finalize(float* __restrict__ out,
                                                   const double* __restrict__ loss_sum,
                                                   const unsigned int* __restrict__ counts) {
    __shared__ double red[256];
    double h = 0.0;
    for (int k = threadIdx.x; k < KCB; k += 256) {
        double p = (double)counts[k] / (double)NVEC;
        h += p * log(p + 1e-10);
    }
    red[threadIdx.x] = h;
    __syncthreads();
    for (int s = 128; s > 0; s >>= 1) {
        if (threadIdx.x < s) red[threadIdx.x] += red[threadIdx.x + s];
        __syncthreads();
    }
    if (threadIdx.x == 0) {
        out[(size_t)NVEC * DIM]     = (float)(0.25 * (*loss_sum) / (double)((size_t)NVEC * DIM));
        out[(size_t)NVEC * DIM + 1] = (float)exp(-red[0]);
    }
}

extern "C" void kernel_launch(void* const* d_in, const int* in_sizes, int n_in,
                              void* d_out, int out_size, void* d_ws, size_t ws_size,
                              hipStream_t stream) {
    const float* inp = (const float*)d_in[0];   // (64,64,64,64) f32
    const float* cb  = (const float*)d_in[1];   // (1024,64) f32
    float* out = (float*)d_out;

    char* ws = (char*)d_ws;
    double*         loss_sum = (double*)(ws + 0);
    unsigned int*   counts   = (unsigned int*)(ws + 8);
    float*          cnf      = (float*)(ws + 4112);
    unsigned short* cbh      = (unsigned short*)(ws + 8224);
    unsigned short* cbl      = (unsigned short*)(ws + 139296);

    hipMemsetAsync(ws, 0, 4112, stream);
    vq_prep<<<dim3(4), dim3(256), 0, stream>>>(cb, cbh, cbl, cnf);
    vq_main<<<dim3(NVEC / 256), dim3(256), 0, stream>>>(inp, cbh, cbl, cnf, cb, out,
                                                        loss_sum, counts);
    vq_finalize<<<dim3(1), dim3(256), 0, stream>>>(out, loss_sum, counts);
}

// Round 3
// 173.463 us; speedup vs baseline: 5.2198x; 1.2188x over previous
//
#include <hip/hip_runtime.h>

#define NVEC (64*64*64)   // 262144 vectors
#define KCB 1024          // codebook size
#define DIM 64            // codebook dim

typedef __attribute__((ext_vector_type(8))) short s16x8;   // 8 x bf16
typedef __attribute__((ext_vector_type(4))) float f32x4;

#define MFMA16(A, B, C) __builtin_amdgcn_mfma_f32_16x16x32_bf16((A), (B), (C), 0, 0, 0)

// ws layout (bytes):
//      0 : double loss_sum
//      8 : uint counts[1024]            (ends 4104, pad 4112)
//   4112 : float cnf[1024]              (ends 8208, pad 8224)
//   8224 : ushort cbA[64][2][64][8]     A-fragment layout of bf16(-2c), 131072 B, ends 139296

__global__ __launch_bounds__(256) void vq_prep(const float* __restrict__ cb,
                                               unsigned short* __restrict__ cbA,
                                               float* __restrict__ cnf) {
    int q = blockIdx.x * 256 + threadIdx.x;      // 0..8191
    int t = q >> 7;                               // code tile 0..63
    int h = (q >> 6) & 1;                         // k-half 0..1
    int l = q & 63;                               // lane slot
    int m = t * 16 + (l & 15);                    // code row
    int d0 = h * 32 + ((l >> 4) & 3) * 8;         // first dim of this lane's 8
    const float* row = cb + (size_t)m * DIM + d0;
    unsigned short* dst = cbA + (size_t)q * 8;
    #pragma unroll
    for (int j = 0; j < 8; ++j) {
        float f = -2.0f * row[j];
        unsigned u = __float_as_uint(f);
        dst[j] = (unsigned short)((u + 0x7fffu + ((u >> 16) & 1u)) >> 16);  // RNE bf16
    }
    if (q < KCB) {
        const float* r2 = cb + (size_t)q * DIM;
        double s = 0.0;
        for (int d = 0; d < DIM; ++d) { double c = (double)r2[d]; s = fma(c, c, s); }
        cnf[q] = (float)s;
    }
}

__global__ __launch_bounds__(256) void vq_main(const float* __restrict__ inp,
                                               const unsigned short* __restrict__ cbA,
                                               const float* __restrict__ cnf,
                                               const float* __restrict__ cb,
                                               float* __restrict__ out,
                                               double* __restrict__ loss_sum,
                                               unsigned int* __restrict__ counts) {
    const int tid  = threadIdx.x;
    const int lane = tid & 63;
    const int w    = tid >> 6;
    const int l15  = lane & 15;
    const int g    = lane >> 4;
    const int gi   = g * 4;
    const int vecbase = blockIdx.x * 256 + w * 64;

    // ---- load this wave's 64 vectors, convert to bf16 B-fragments ----
    // B[k][n]: lane l holds n=l&15, k=(l>>4)*8+j; half h covers dims h*32..h*32+31
    s16x8 xb[4][2];
    #pragma unroll
    for (int v = 0; v < 4; ++v) {
        const float4* xp = (const float4*)(inp + (size_t)(vecbase + v * 16 + l15) * DIM);
        float4 a0 = xp[g * 2], a1 = xp[g * 2 + 1];
        float4 a2 = xp[8 + g * 2], a3 = xp[8 + g * 2 + 1];
        float f0[8] = {a0.x, a0.y, a0.z, a0.w, a1.x, a1.y, a1.z, a1.w};
        float f1[8] = {a2.x, a2.y, a2.z, a2.w, a3.x, a3.y, a3.z, a3.w};
        unsigned w0[4], w1[4];
        #pragma unroll
        for (int p = 0; p < 4; ++p) {
            unsigned r0, r1;
            asm("v_cvt_pk_bf16_f32 %0, %1, %2" : "=v"(r0) : "v"(f0[2*p]), "v"(f0[2*p+1]));
            asm("v_cvt_pk_bf16_f32 %0, %1, %2" : "=v"(r1) : "v"(f1[2*p]), "v"(f1[2*p+1]));
            w0[p] = r0; w1[p] = r1;
        }
        xb[v][0] = *(const s16x8*)w0;
        xb[v][1] = *(const s16x8*)w1;
    }

    float best[4] = {3.4e38f, 3.4e38f, 3.4e38f, 3.4e38f};

    const s16x8* Af = (const s16x8*)cbA;   // fragment index = (t*2+h)*64 + lane

    // ---- K sweep: 64 code tiles, no LDS, A-frags stream from L2 ----
    #pragma unroll 2
    for (int t = 0; t < 64; ++t) {
        s16x8 A0 = Af[(t * 2 + 0) * 64 + lane];
        s16x8 A1 = Af[(t * 2 + 1) * 64 + lane];
        f32x4 cn4 = *(const f32x4*)(cnf + t * 16 + gi);   // acc init = ||c||^2

        f32x4 acc[4];
        #pragma unroll
        for (int v = 0; v < 4; ++v) acc[v] = cn4;
        #pragma unroll
        for (int v = 0; v < 4; ++v) acc[v] = MFMA16(A0, xb[v][0], acc[v]);
        #pragma unroll
        for (int v = 0; v < 4; ++v) acc[v] = MFMA16(A1, xb[v][1], acc[v]);

        // pack code index into low 10 mantissa bits -> 1 min/candidate
        int kb = (t << 4) | gi;   // code index base for this lane-group
        #pragma unroll
        for (int v = 0; v < 4; ++v) {
            #pragma unroll
            for (int r = 0; r < 4; ++r) {
                unsigned pb = (__float_as_uint(acc[v][r]) & 0xFFFFFC00u)
                            | (unsigned)(kb + r);
                best[v] = fminf(best[v], __uint_as_float(pb));
            }
        }
    }

    // ---- reduce across the 4 lane groups (codes split by g) ----
    int bidx[4];
    #pragma unroll
    for (int v = 0; v < 4; ++v) {
        best[v] = fminf(best[v], __shfl_xor(best[v], 16));
        best[v] = fminf(best[v], __shfl_xor(best[v], 32));
        bidx[v] = (int)(__float_as_uint(best[v]) & 1023u);
    }

    // ---- coalesced output write: wave region = 64 vectors contiguous ----
    float4* ob4 = (float4*)(out + (size_t)vecbase * DIM);
    #pragma unroll
    for (int v = 0; v < 4; ++v) {
        #pragma unroll
        for (int i = 0; i < 4; ++i) {
            int wv = i * 4 + g;
            int bk = __shfl(bidx[v], wv);
            float4 q = ((const float4*)(cb + (size_t)bk * DIM))[l15];
            ob4[(v * 16 + wv) * 16 + l15] = q;
        }
    }

    // ---- loss from bf16 x (rel err ~1e-6) + counts ----
    float lsum = 0.0f;
    #pragma unroll
    for (int v = 0; v < 4; ++v) {
        int bk = bidx[v];
        const float4* cr = (const float4*)(cb + (size_t)bk * DIM);
        float4 c0 = cr[g * 2], c1 = cr[g * 2 + 1];
        float4 c2 = cr[8 + g * 2], c3 = cr[8 + g * 2 + 1];
        float cf0[8] = {c0.x, c0.y, c0.z, c0.w, c1.x, c1.y, c1.z, c1.w};
        float cf1[8] = {c2.x, c2.y, c2.z, c2.w, c3.x, c3.y, c3.z, c3.w};
        const unsigned* w0 = (const unsigned*)&xb[v][0];
        const unsigned* w1 = (const unsigned*)&xb[v][1];
        #pragma unroll
        for (int p = 0; p < 4; ++p) {
            float xlo = __uint_as_float(w0[p] << 16);
            float xhi = __uint_as_float(w0[p] & 0xFFFF0000u);
            float d0 = xlo - cf0[2*p],   d1 = xhi - cf0[2*p+1];
            lsum = fmaf(d0, d0, lsum);
            lsum = fmaf(d1, d1, lsum);
            float ylo = __uint_as_float(w1[p] << 16);
            float yhi = __uint_as_float(w1[p] & 0xFFFF0000u);
            float e0 = ylo - cf1[2*p],   e1 = yhi - cf1[2*p+1];
            lsum = fmaf(e0, e0, lsum);
            lsum = fmaf(e1, e1, lsum);
        }
        if (g == 0) atomicAdd(&counts[bk], 1u);
    }
    double dsum = (double)lsum;
    #pragma unroll
    for (int off = 32; off > 0; off >>= 1) dsum += __shfl_xor(dsum, off);
    if (lane == 0) atomicAdd(loss_sum, dsum);
}

__global__ __launch_bounds__(256) void vq_finalize(float* __restrict__ out,
                                                   const double* __restrict__ loss_sum,
                                                   const unsigned int* __restrict__ counts) {
    __shared__ double red[256];
    double h = 0.0;
    for (int k = threadIdx.x; k < KCB; k += 256) {
        double p = (double)counts[k] / (double)NVEC;
        h += p * log(p + 1e-10);
    }
    red[threadIdx.x] = h;
    __syncthreads();
    for (int s = 128; s > 0; s >>= 1) {
        if (threadIdx.x < s) red[threadIdx.x] += red[threadIdx.x + s];
        __syncthreads();
    }
    if (threadIdx.x == 0) {
        out[(size_t)NVEC * DIM]     = (float)(0.25 * (*loss_sum) / (double)((size_t)NVEC * DIM));
        out[(size_t)NVEC * DIM + 1] = (float)exp(-red[0]);
    }
}

extern "C" void kernel_launch(void* const* d_in, const int* in_sizes, int n_in,
                              void* d_out, int out_size, void* d_ws, size_t ws_size,
                              hipStream_t stream) {
    const float* inp = (const float*)d_in[0];   // (64,64,64,64) f32
    const float* cb  = (const float*)d_in[1];   // (1024,64) f32
    float* out = (float*)d_out;

    char* ws = (char*)d_ws;
    double*         loss_sum = (double*)(ws + 0);
    unsigned int*   counts   = (unsigned int*)(ws + 8);
    float*          cnf      = (float*)(ws + 4112);
    unsigned short* cbA      = (unsigned short*)(ws + 8224);

    hipMemsetAsync(ws, 0, 4112, stream);
    vq_prep<<<dim3(32), dim3(256), 0, stream>>>(cb, cbA, cnf);
    vq_main<<<dim3(NVEC / 256), dim3(256), 0, stream>>>(inp, cbA, cnf, cb, out,
                                                        loss_sum, counts);
    vq_finalize<<<dim3(1), dim3(256), 0, stream>>>(out, loss_sum, counts);
}